// Round 1
// baseline (1005.104 us; speedup 1.0000x reference)
//
#include <hip/hip_runtime.h>
#include <math.h>

#define CLS_THRESH 0.05f

// One wave (64 lanes) per (b,n) row:
//   - cooperative float4-vectorized max+argmax over C classes
//   - butterfly shuffle reduce carrying (val, idx), first-occurrence tie-break
//   - lane 0 fuses box regression + clip + mask and writes all outputs
__global__ __launch_bounds__(256) void infer_transform_kernel(
    const float* __restrict__ cls,    // [B, N, C]
    const float* __restrict__ reg,    // [B, N, 4]
    const float* __restrict__ anch,   // [1, N, 4]
    float* __restrict__ out,          // boxes[B*N*4] | scores[B*N] | cls_idx[B*N] | mask[B*N]
    int B, int N, int C, float img_w, float img_h)
{
    const int wavesPerBlock = blockDim.x >> 6;
    const int wave = threadIdx.x >> 6;
    const int lane = threadIdx.x & 63;
    const long long rows = (long long)B * N;
    const long long row  = (long long)blockIdx.x * wavesPerBlock + wave;
    if (row >= rows) return;

    const int n = (int)(row % (long long)N);
    const float* __restrict__ crow = cls + row * (long long)C;

    // ---- lane-local max + first-index over strided float4 chunks ----
    float best = -INFINITY;
    int   bidx = 0x7fffffff;
    const int nvec = C >> 2;                 // 125 for C=500
    for (int i = lane; i < nvec; i += 64) {  // 2 iterations, fully coalesced 16B/lane
        const float4 v = reinterpret_cast<const float4*>(crow)[i];
        const int base = i << 2;
        if (v.x > best) { best = v.x; bidx = base;     }
        if (v.y > best) { best = v.y; bidx = base + 1; }
        if (v.z > best) { best = v.z; bidx = base + 2; }
        if (v.w > best) { best = v.w; bidx = base + 3; }
    }
    for (int i = (nvec << 2) + lane; i < C; i += 64) {  // scalar tail (none for C=500)
        const float v = crow[i];
        if (v > best) { best = v; bidx = i; }
    }

    // ---- 64-lane butterfly reduce: max value, smallest index on ties ----
    #pragma unroll
    for (int off = 32; off >= 1; off >>= 1) {
        const float ov = __shfl_xor(best, off, 64);
        const int   oi = __shfl_xor(bidx, off, 64);
        if (ov > best || (ov == best && oi < bidx)) { best = ov; bidx = oi; }
    }

    // ---- lane 0: box transform, clip, mask, write ----
    if (lane == 0) {
        const float4 rg = reinterpret_cast<const float4*>(reg)[row];
        const float4 an = reinterpret_cast<const float4*>(anch)[n];

        const float w  = an.z - an.x;
        const float h  = an.w - an.y;
        const float cx = an.x + 0.5f * w;
        const float cy = an.y + 0.5f * h;

        const float dx = rg.x * 0.1f;
        const float dy = rg.y * 0.1f;
        const float dw = rg.z * 0.2f;
        const float dh = rg.w * 0.2f;

        const float pcx = cx + dx * w;
        const float pcy = cy + dy * h;
        const float pw  = expf(dw) * w;
        const float ph  = expf(dh) * h;

        float x1 = pcx - 0.5f * pw;
        float y1 = pcy - 0.5f * ph;
        float x2 = pcx + 0.5f * pw;
        float y2 = pcy + 0.5f * ph;

        x1 = fminf(fmaxf(x1, 0.0f), img_w);
        y1 = fminf(fmaxf(y1, 0.0f), img_h);
        x2 = fminf(fmaxf(x2, 0.0f), img_w);
        y2 = fminf(fmaxf(y2, 0.0f), img_h);

        const float m = (best > CLS_THRESH) ? 1.0f : 0.0f;

        reinterpret_cast<float4*>(out)[row] = make_float4(x1 * m, y1 * m, x2 * m, y2 * m);
        out[rows * 4 + row] = best * m;       // scores_m
        out[rows * 5 + row] = (float)bidx;    // cls_idx
        out[rows * 6 + row] = m;              // mask
    }
}

extern "C" void kernel_launch(void* const* d_in, const int* in_sizes, int n_in,
                              void* d_out, int out_size, void* d_ws, size_t ws_size,
                              hipStream_t stream) {
    // Inputs in setup_inputs() order: imgs, classifications, regressions, anchors
    const float* cls  = (const float*)d_in[1];
    const float* reg  = (const float*)d_in[2];
    const float* anch = (const float*)d_in[3];
    float* out = (float*)d_out;

    // Derive shapes from flat sizes (imgs only contributes H/W)
    const int N  = in_sizes[3] / 4;                       // anchors: [1, N, 4]
    const int BN = in_sizes[2] / 4;                       // regressions: [B, N, 4]
    const int B  = BN / N;
    const int C  = (int)((long long)in_sizes[1] / BN);    // classifications: [B, N, C]
    const long long hw = (long long)in_sizes[0] / (3LL * B);
    const int W = (int)(sqrt((double)hw) + 0.5);          // imgs: [B, 3, H, W], H == W
    const float img_w = (float)W, img_h = (float)W;

    const int wavesPerBlock = 4;                          // 256 threads
    const int blocks = (BN + wavesPerBlock - 1) / wavesPerBlock;
    infer_transform_kernel<<<blocks, 256, 0, stream>>>(cls, reg, anch, out,
                                                       B, N, C, img_w, img_h);
}